// Round 4
// baseline (473.901 us; speedup 1.0000x reference)
//
#include <hip/hip_runtime.h>

// GCN 2-layer forward on MI355X (gfx950).
// R4: agg1 MLP attack — 2 waves/node (128ch each, ushort2 gathers), edge loop
//     unroll x8 with batched uint4 epk loads, LDS cross-wave combine.

#define NN 100000
#define NE 1600000
#define INC 768
#define HID 256
#define NCLS 8
#define NBLK 391  // ceil(NN/256)

typedef short bf16x8 __attribute__((ext_vector_type(8)));
typedef float f32x4 __attribute__((ext_vector_type(4)));

__device__ __forceinline__ unsigned short f2bf(float f) {
  unsigned int u = __float_as_uint(f);
  unsigned int r = (u + 0x7FFFu + ((u >> 16) & 1u)) >> 16;  // RNE
  return (unsigned short)r;
}
__device__ __forceinline__ float bf2f(unsigned short h) {
  return __uint_as_float(((unsigned int)h) << 16);
}

// ---------- degree / norm ----------
__global__ __launch_bounds__(256) void k_zero(int* __restrict__ cnt) {
  int i = blockIdx.x * 256 + threadIdx.x;
  if (i < NN) cnt[i] = 0;
}
__global__ __launch_bounds__(256) void k_count(const int* __restrict__ ei, int* __restrict__ cnt) {
  int e = blockIdx.x * 256 + threadIdx.x;
  if (e < NE) atomicAdd(&cnt[ei[NE + e]], 1);  // col = targets
}
__global__ __launch_bounds__(256) void k_dinv(const int* __restrict__ cnt, float* __restrict__ dinv) {
  int i = blockIdx.x * 256 + threadIdx.x;
  if (i < NN) dinv[i] = rsqrtf((float)cnt[i] + 1.0f);  // +1 self-loop
}

// ---------- CSR: 3-phase exclusive scan ----------
__global__ __launch_bounds__(256) void k_scan1(const int* __restrict__ cnt, int* __restrict__ bsum) {
  __shared__ int s[256];
  int i = blockIdx.x * 256 + threadIdx.x;
  s[threadIdx.x] = (i < NN) ? cnt[i] : 0;
  __syncthreads();
#pragma unroll
  for (int off = 128; off > 0; off >>= 1) {
    if (threadIdx.x < off) s[threadIdx.x] += s[threadIdx.x + off];
    __syncthreads();
  }
  if (threadIdx.x == 0) bsum[blockIdx.x] = s[0];
}
__global__ __launch_bounds__(512) void k_scan2(const int* __restrict__ bsum, int* __restrict__ boff,
                                               int* __restrict__ rowptr) {
  __shared__ int s[512];
  int tid = threadIdx.x;
  int v = (tid < NBLK) ? bsum[tid] : 0;
  s[tid] = v;
  __syncthreads();
#pragma unroll
  for (int off = 1; off < 512; off <<= 1) {
    int t = (tid >= off) ? s[tid - off] : 0;
    __syncthreads();
    s[tid] += t;
    __syncthreads();
  }
  if (tid < NBLK) boff[tid] = s[tid] - v;
  if (tid == NBLK - 1) rowptr[NN] = s[tid];
}
__global__ __launch_bounds__(256) void k_scan3(const int* __restrict__ cnt, const int* __restrict__ boff,
                                               int* __restrict__ rowptr, int* __restrict__ cursor) {
  __shared__ int s[256];
  int i = blockIdx.x * 256 + threadIdx.x;
  int v = (i < NN) ? cnt[i] : 0;
  s[threadIdx.x] = v;
  __syncthreads();
#pragma unroll
  for (int off = 1; off < 256; off <<= 1) {
    int t = (threadIdx.x >= off) ? s[threadIdx.x - off] : 0;
    __syncthreads();
    s[threadIdx.x] += t;
    __syncthreads();
  }
  if (i < NN) {
    int e = boff[blockIdx.x] + s[threadIdx.x] - v;
    rowptr[i] = e;
    cursor[i] = e;
  }
}
// fill: per-edge packed (src, dinv[src]*dinv[col])
__global__ __launch_bounds__(256) void k_fill(const int* __restrict__ ei, const float* __restrict__ dinv,
                                              int* __restrict__ cursor, int2* __restrict__ epk) {
  int e = blockIdx.x * 256 + threadIdx.x;
  if (e >= NE) return;
  int r = ei[e];         // source
  int c = ei[NE + e];    // target
  float w = dinv[r] * dinv[c];
  int pos = atomicAdd(&cursor[c], 1);
  epk[pos] = make_int2(r, __float_as_int(w));
}

// ---------- W1 transpose+cast ----------
__global__ __launch_bounds__(256) void k_w1t(const float* __restrict__ W1, unsigned short* __restrict__ w1t) {
  int t = blockIdx.x * 256 + threadIdx.x;
  if (t >= INC * HID) return;
  int k = t / HID, n = t % HID;
  w1t[n * INC + k] = f2bf(W1[t]);
}

// ---------- GEMM1: h1[NN][256] (bf16) = x @ W1 ---------- (R3 pipelined, unchanged)
__global__ __launch_bounds__(512) void k_gemm1(const float* __restrict__ x,
                                               const unsigned short* __restrict__ w1t,
                                               unsigned short* __restrict__ h1) {
  __shared__ char smem[49152];
  unsigned short* As = (unsigned short*)smem;
  unsigned short* Bs = (unsigned short*)(smem + 16384);
  const int tid = threadIdx.x;
  const int lane = tid & 63;
  const int wid = tid >> 6;
  const int wm = wid >> 2;
  const int wn = wid & 3;
  const long bm = blockIdx.x;

  const int ar0 = tid >> 3, as7 = tid & 7;
  const int ar1 = (tid + 512) >> 3;
  long arow0 = bm * 128 + ar0; if (arow0 > NN - 1) arow0 = NN - 1;
  long arow1 = bm * 128 + ar1; if (arow1 > NN - 1) arow1 = NN - 1;
  const float* gA0 = x + arow0 * INC + as7 * 8;
  const float* gA1 = x + arow1 * INC + as7 * 8;
  const int aoff0 = (ar0 << 7) | ((as7 ^ (ar0 & 7)) << 4);
  const int aoff1 = (ar1 << 7) | ((as7 ^ (ar1 & 7)) << 4);

  f32x4 acc[4][4];
#pragma unroll
  for (int m = 0; m < 4; m++)
#pragma unroll
    for (int n = 0; n < 4; n++) acc[m][n] = (f32x4){0.f, 0.f, 0.f, 0.f};

  float4 fa00, fa01, fa10, fa11;
  uint4 rb0, rb1, rb2, rb3;

#define LOAD_AB(KT)                                                        \
  do {                                                                     \
    fa00 = *(const float4*)(gA0 + (KT));                                   \
    fa01 = *(const float4*)(gA0 + (KT) + 4);                               \
    fa10 = *(const float4*)(gA1 + (KT));                                   \
    fa11 = *(const float4*)(gA1 + (KT) + 4);                               \
    rb0 = *(const uint4*)(w1t + (long)(tid >> 3) * INC + (KT) + (tid & 7) * 8);            \
    rb1 = *(const uint4*)(w1t + (long)((tid + 512) >> 3) * INC + (KT) + (tid & 7) * 8);    \
    rb2 = *(const uint4*)(w1t + (long)((tid + 1024) >> 3) * INC + (KT) + (tid & 7) * 8);   \
    rb3 = *(const uint4*)(w1t + (long)((tid + 1536) >> 3) * INC + (KT) + (tid & 7) * 8);   \
  } while (0)

  LOAD_AB(0);

  for (int kt = 0; kt < INC; kt += 64) {
    {
      union { unsigned short us[8]; uint4 v; } u;
      u.us[0] = f2bf(fa00.x); u.us[1] = f2bf(fa00.y); u.us[2] = f2bf(fa00.z); u.us[3] = f2bf(fa00.w);
      u.us[4] = f2bf(fa01.x); u.us[5] = f2bf(fa01.y); u.us[6] = f2bf(fa01.z); u.us[7] = f2bf(fa01.w);
      *(uint4*)((char*)As + aoff0) = u.v;
      u.us[0] = f2bf(fa10.x); u.us[1] = f2bf(fa10.y); u.us[2] = f2bf(fa10.z); u.us[3] = f2bf(fa10.w);
      u.us[4] = f2bf(fa11.x); u.us[5] = f2bf(fa11.y); u.us[6] = f2bf(fa11.z); u.us[7] = f2bf(fa11.w);
      *(uint4*)((char*)As + aoff1) = u.v;
    }
    {
      int r0 = tid >> 3, s7 = tid & 7;
      *(uint4*)((char*)Bs + ((r0 << 7) | ((s7 ^ (r0 & 7)) << 4))) = rb0;
      int r1 = (tid + 512) >> 3;
      *(uint4*)((char*)Bs + ((r1 << 7) | ((s7 ^ (r1 & 7)) << 4))) = rb1;
      int r2 = (tid + 1024) >> 3;
      *(uint4*)((char*)Bs + ((r2 << 7) | ((s7 ^ (r2 & 7)) << 4))) = rb2;
      int r3 = (tid + 1536) >> 3;
      *(uint4*)((char*)Bs + ((r3 << 7) | ((s7 ^ (r3 & 7)) << 4))) = rb3;
    }
    __syncthreads();
    if (kt + 64 < INC) LOAD_AB(kt + 64);
#pragma unroll
    for (int half = 0; half < 2; half++) {
      bf16x8 af[4], bff[4];
      int j = (half << 2) + (lane >> 4);
#pragma unroll
      for (int m = 0; m < 4; m++) {
        int row = wm * 64 + m * 16 + (lane & 15);
        int off = (row << 7) | ((j ^ (row & 7)) << 4);
        af[m] = *(const bf16x8*)((const char*)As + off);
      }
#pragma unroll
      for (int n = 0; n < 4; n++) {
        int row = wn * 64 + n * 16 + (lane & 15);
        int off = (row << 7) | ((j ^ (row & 7)) << 4);
        bff[n] = *(const bf16x8*)((const char*)Bs + off);
      }
#pragma unroll
      for (int m = 0; m < 4; m++)
#pragma unroll
        for (int n = 0; n < 4; n++)
          acc[m][n] = __builtin_amdgcn_mfma_f32_16x16x32_bf16(af[m], bff[n], acc[m][n], 0, 0, 0);
    }
    __syncthreads();
  }
#undef LOAD_AB

  unsigned short* Os = (unsigned short*)smem;  // [64][264]
#pragma unroll
  for (int chunk = 0; chunk < 2; chunk++) {
    if (wm == chunk) {
#pragma unroll
      for (int m = 0; m < 4; m++)
#pragma unroll
        for (int n = 0; n < 4; n++) {
          int lrow = m * 16 + ((lane >> 4) << 2);
          int lcol = wn * 64 + n * 16 + (lane & 15);
#pragma unroll
          for (int r = 0; r < 4; r++)
            Os[(lrow + r) * 264 + lcol] = f2bf(acc[m][n][r]);
        }
    }
    __syncthreads();
    {
      int r = tid >> 3, s = tid & 7;
      long grow = bm * 128 + chunk * 64 + r;
      if (grow < NN) {
        unsigned short* dst = h1 + grow * HID;
#pragma unroll
        for (int i = 0; i < 4; i++) {
          int seg = s + i * 8;
          *(uint4*)(dst + seg * 8) = *(const uint4*)((const char*)Os + (long)r * 528 + seg * 16);
        }
      }
    }
    __syncthreads();
  }
}

// ---------- agg1 fused with relu+b1+W2 ----------
// 2 waves per node (128 ch each, ushort2/lane), unroll x8, LDS combine.
__global__ __launch_bounds__(256) void k_agg1(const unsigned short* __restrict__ h1,
                                              const float* __restrict__ dinv,
                                              const int* __restrict__ rowptr,
                                              const int2* __restrict__ epk,
                                              const float* __restrict__ b1,
                                              const float* __restrict__ W2,
                                              float* __restrict__ h2) {
  __shared__ float comb[2][2][8];  // [node_local][half][class]
  int wv = threadIdx.x >> 6;       // 0..3
  int nl = wv >> 1;                // node_local 0..1
  int half = wv & 1;
  int lane = threadIdx.x & 63;
  long node = (long)blockIdx.x * 2 + nl;
  if (node >= NN) { return; }
  int c2 = half * 128 + (lane << 1);  // channel pair base
  float di = dinv[node];

  const unsigned short* hb = h1 + c2;
  ushort2 hv = *(const ushort2*)(hb + node * HID);
  float self = di * di;
  float a0 = self * bf2f(hv.x), a1 = self * bf2f(hv.y);

  int e = rowptr[node], e1 = rowptr[node + 1];
  // parity peel so uint4 epk loads are 16B-aligned
  if ((e & 1) && e < e1) {
    int2 q = epk[e];
    float w = __int_as_float(q.y);
    ushort2 g = *(const ushort2*)(hb + (long)q.x * HID);
    a0 += w * bf2f(g.x); a1 += w * bf2f(g.y);
    e++;
  }
  for (; e + 8 <= e1; e += 8) {
    uint4 p0 = *(const uint4*)(epk + e);
    uint4 p1 = *(const uint4*)(epk + e + 2);
    uint4 p2 = *(const uint4*)(epk + e + 4);
    uint4 p3 = *(const uint4*)(epk + e + 6);
    ushort2 g0 = *(const ushort2*)(hb + (long)(int)p0.x * HID);
    ushort2 g1 = *(const ushort2*)(hb + (long)(int)p0.z * HID);
    ushort2 g2 = *(const ushort2*)(hb + (long)(int)p1.x * HID);
    ushort2 g3 = *(const ushort2*)(hb + (long)(int)p1.z * HID);
    ushort2 g4 = *(const ushort2*)(hb + (long)(int)p2.x * HID);
    ushort2 g5 = *(const ushort2*)(hb + (long)(int)p2.z * HID);
    ushort2 g6 = *(const ushort2*)(hb + (long)(int)p3.x * HID);
    ushort2 g7 = *(const ushort2*)(hb + (long)(int)p3.z * HID);
    float w0 = __uint_as_float(p0.y), w1 = __uint_as_float(p0.w);
    float w2 = __uint_as_float(p1.y), w3 = __uint_as_float(p1.w);
    float w4 = __uint_as_float(p2.y), w5 = __uint_as_float(p2.w);
    float w6 = __uint_as_float(p3.y), w7 = __uint_as_float(p3.w);
    a0 += w0 * bf2f(g0.x) + w1 * bf2f(g1.x) + w2 * bf2f(g2.x) + w3 * bf2f(g3.x) +
          w4 * bf2f(g4.x) + w5 * bf2f(g5.x) + w6 * bf2f(g6.x) + w7 * bf2f(g7.x);
    a1 += w0 * bf2f(g0.y) + w1 * bf2f(g1.y) + w2 * bf2f(g2.y) + w3 * bf2f(g3.y) +
          w4 * bf2f(g4.y) + w5 * bf2f(g5.y) + w6 * bf2f(g6.y) + w7 * bf2f(g7.y);
  }
  for (; e < e1; e++) {
    int2 q = epk[e];
    float w = __int_as_float(q.y);
    ushort2 g = *(const ushort2*)(hb + (long)q.x * HID);
    a0 += w * bf2f(g.x); a1 += w * bf2f(g.y);
  }

  // relu(a + b1), then 2ch x 8cls partials
  float2 bv = *(const float2*)(b1 + c2);
  float v0 = a0 + bv.x; v0 = v0 > 0.f ? v0 : 0.f;
  float v1 = a1 + bv.y; v1 = v1 > 0.f ? v1 : 0.f;
  const float4* wp = (const float4*)(W2 + ((long)c2 << 3));  // rows c2, c2+1
  float4 r0a = wp[0], r0b = wp[1], r1a = wp[2], r1b = wp[3];
  float p[8];
  p[0] = v0 * r0a.x + v1 * r1a.x;
  p[1] = v0 * r0a.y + v1 * r1a.y;
  p[2] = v0 * r0a.z + v1 * r1a.z;
  p[3] = v0 * r0a.w + v1 * r1a.w;
  p[4] = v0 * r0b.x + v1 * r1b.x;
  p[5] = v0 * r0b.y + v1 * r1b.y;
  p[6] = v0 * r0b.z + v1 * r1b.z;
  p[7] = v0 * r0b.w + v1 * r1b.w;
#pragma unroll
  for (int c = 0; c < 8; c++)
#pragma unroll
    for (int off = 1; off < 64; off <<= 1) p[c] += __shfl_xor(p[c], off, 64);
  if (lane < 8) {
    float o = p[0];
    o = (lane == 1) ? p[1] : o;
    o = (lane == 2) ? p[2] : o;
    o = (lane == 3) ? p[3] : o;
    o = (lane == 4) ? p[4] : o;
    o = (lane == 5) ? p[5] : o;
    o = (lane == 6) ? p[6] : o;
    o = (lane == 7) ? p[7] : o;
    comb[nl][half][lane] = o;
  }
  __syncthreads();
  if (half == 0 && lane < 8)
    h2[node * NCLS + lane] = comb[nl][0][lane] + comb[nl][1][lane];
}

// ---------- agg2 + bias -> out ----------
__global__ __launch_bounds__(256) void k_agg2(const float* __restrict__ h2,
                                              const float* __restrict__ dinv,
                                              const int* __restrict__ rowptr,
                                              const int2* __restrict__ epk,
                                              const float* __restrict__ b2,
                                              float* __restrict__ out) {
  long t = (long)blockIdx.x * 256 + threadIdx.x;
  long i = t >> 3;
  int c = (int)(t & 7);
  if (i >= NN) return;
  float di = dinv[i];
  float s = di * di * h2[i * NCLS + c];
  int e0 = rowptr[i], e1 = rowptr[i + 1];
  int e = e0;
  for (; e + 4 <= e1; e += 4) {
    int2 q0 = epk[e], q1 = epk[e + 1], q2 = epk[e + 2], q3 = epk[e + 3];
    float g0 = h2[(long)q0.x * NCLS + c], g1 = h2[(long)q1.x * NCLS + c];
    float g2 = h2[(long)q2.x * NCLS + c], g3 = h2[(long)q3.x * NCLS + c];
    s += __int_as_float(q0.y) * g0 + __int_as_float(q1.y) * g1 +
         __int_as_float(q2.y) * g2 + __int_as_float(q3.y) * g3;
  }
  for (; e < e1; e++) {
    int2 q = epk[e];
    s += __int_as_float(q.y) * h2[(long)q.x * NCLS + c];
  }
  out[i * NCLS + c] = s + b2[c];
}

extern "C" void kernel_launch(void* const* d_in, const int* in_sizes, int n_in,
                              void* d_out, int out_size, void* d_ws, size_t ws_size,
                              hipStream_t stream) {
  (void)in_sizes; (void)n_in; (void)out_size; (void)ws_size;
  const float* x  = (const float*)d_in[0];
  const int*   ei = (const int*)d_in[1];
  const float* W1 = (const float*)d_in[2];
  const float* b1 = (const float*)d_in[3];
  const float* W2 = (const float*)d_in[4];
  const float* b2 = (const float*)d_in[5];
  float* out = (float*)d_out;
  char* ws = (char*)d_ws;

  unsigned short* h1   = (unsigned short*)(ws + 0L);          // 51,200,000
  float* h2            = (float*)(ws + 51200000L);            // 3,200,000
  float* dinv          = (float*)(ws + 54400000L);            // 400,000
  int*   cnt           = (int*)(ws + 54800000L);              // 400,000
  int*   rowptr        = (int*)(ws + 55200000L);              // 400,004 (+pad)
  int*   cursor        = (int*)(ws + 55600128L);              // 400,000
  int2*  epk           = (int2*)(ws + 56000128L);             // 12,800,000
  unsigned short* w1t  = (unsigned short*)(ws + 68800128L);   // 393,216
  int*   bsum          = (int*)(ws + 69195008L);              // 1,564
  int*   boff          = (int*)(ws + 69196608L);              // 1,564

  k_zero<<<(NN + 255) / 256, 256, 0, stream>>>(cnt);
  k_count<<<(NE + 255) / 256, 256, 0, stream>>>(ei, cnt);
  k_dinv<<<(NN + 255) / 256, 256, 0, stream>>>(cnt, dinv);
  k_scan1<<<NBLK, 256, 0, stream>>>(cnt, bsum);
  k_scan2<<<1, 512, 0, stream>>>(bsum, boff, rowptr);
  k_scan3<<<NBLK, 256, 0, stream>>>(cnt, boff, rowptr, cursor);
  k_fill<<<(NE + 255) / 256, 256, 0, stream>>>(ei, dinv, cursor, epk);
  k_w1t<<<(INC * HID + 255) / 256, 256, 0, stream>>>(W1, w1t);
  k_gemm1<<<782, 512, 0, stream>>>(x, w1t, h1);
  k_agg1<<<(NN + 1) / 2, 256, 0, stream>>>(h1, dinv, rowptr, epk, b1, W2, h2);
  k_agg2<<<(NN * NCLS + 255) / 256, 256, 0, stream>>>(h2, dinv, rowptr, epk, b2, out);
}

// Round 5
// 458.028 us; speedup vs baseline: 1.0347x; 1.0347x over previous
//
#include <hip/hip_runtime.h>

// GCN 2-layer forward on MI355X (gfx950).
// R5: agg1 back to R3 shape (wave/node, ushort4 full-row gather) + edge unroll x8
//     (8 gathers in flight); agg2 unroll x8; k_zero -> memset node; dinv fused
//     into scan1 (-2 launches).

#define NN 100000
#define NE 1600000
#define INC 768
#define HID 256
#define NCLS 8
#define NBLK 391  // ceil(NN/256)

typedef short bf16x8 __attribute__((ext_vector_type(8)));
typedef float f32x4 __attribute__((ext_vector_type(4)));

__device__ __forceinline__ unsigned short f2bf(float f) {
  unsigned int u = __float_as_uint(f);
  unsigned int r = (u + 0x7FFFu + ((u >> 16) & 1u)) >> 16;  // RNE
  return (unsigned short)r;
}
__device__ __forceinline__ float bf2f(unsigned short h) {
  return __uint_as_float(((unsigned int)h) << 16);
}

// ---------- degree / norm ----------
__global__ __launch_bounds__(256) void k_count(const int* __restrict__ ei, int* __restrict__ cnt) {
  int e = blockIdx.x * 256 + threadIdx.x;
  if (e < NE) atomicAdd(&cnt[ei[NE + e]], 1);  // col = targets
}

// ---------- CSR: 3-phase exclusive scan (scan1 also emits dinv) ----------
__global__ __launch_bounds__(256) void k_scan1(const int* __restrict__ cnt, int* __restrict__ bsum,
                                               float* __restrict__ dinv) {
  __shared__ int s[256];
  int i = blockIdx.x * 256 + threadIdx.x;
  int v = (i < NN) ? cnt[i] : 0;
  if (i < NN) dinv[i] = rsqrtf((float)v + 1.0f);  // +1 self-loop
  s[threadIdx.x] = v;
  __syncthreads();
#pragma unroll
  for (int off = 128; off > 0; off >>= 1) {
    if (threadIdx.x < off) s[threadIdx.x] += s[threadIdx.x + off];
    __syncthreads();
  }
  if (threadIdx.x == 0) bsum[blockIdx.x] = s[0];
}
__global__ __launch_bounds__(512) void k_scan2(const int* __restrict__ bsum, int* __restrict__ boff,
                                               int* __restrict__ rowptr) {
  __shared__ int s[512];
  int tid = threadIdx.x;
  int v = (tid < NBLK) ? bsum[tid] : 0;
  s[tid] = v;
  __syncthreads();
#pragma unroll
  for (int off = 1; off < 512; off <<= 1) {
    int t = (tid >= off) ? s[tid - off] : 0;
    __syncthreads();
    s[tid] += t;
    __syncthreads();
  }
  if (tid < NBLK) boff[tid] = s[tid] - v;
  if (tid == NBLK - 1) rowptr[NN] = s[tid];
}
__global__ __launch_bounds__(256) void k_scan3(const int* __restrict__ cnt, const int* __restrict__ boff,
                                               int* __restrict__ rowptr, int* __restrict__ cursor) {
  __shared__ int s[256];
  int i = blockIdx.x * 256 + threadIdx.x;
  int v = (i < NN) ? cnt[i] : 0;
  s[threadIdx.x] = v;
  __syncthreads();
#pragma unroll
  for (int off = 1; off < 256; off <<= 1) {
    int t = (threadIdx.x >= off) ? s[threadIdx.x - off] : 0;
    __syncthreads();
    s[threadIdx.x] += t;
    __syncthreads();
  }
  if (i < NN) {
    int e = boff[blockIdx.x] + s[threadIdx.x] - v;
    rowptr[i] = e;
    cursor[i] = e;
  }
}
// fill: per-edge packed (src, dinv[src]*dinv[col])
__global__ __launch_bounds__(256) void k_fill(const int* __restrict__ ei, const float* __restrict__ dinv,
                                              int* __restrict__ cursor, int2* __restrict__ epk) {
  int e = blockIdx.x * 256 + threadIdx.x;
  if (e >= NE) return;
  int r = ei[e];         // source
  int c = ei[NE + e];    // target
  float w = dinv[r] * dinv[c];
  int pos = atomicAdd(&cursor[c], 1);
  epk[pos] = make_int2(r, __float_as_int(w));
}

// ---------- W1 transpose+cast ----------
__global__ __launch_bounds__(256) void k_w1t(const float* __restrict__ W1, unsigned short* __restrict__ w1t) {
  int t = blockIdx.x * 256 + threadIdx.x;
  if (t >= INC * HID) return;
  int k = t / HID, n = t % HID;
  w1t[n * INC + k] = f2bf(W1[t]);
}

// ---------- GEMM1: h1[NN][256] (bf16) = x @ W1 ---------- (R3 pipelined)
__global__ __launch_bounds__(512) void k_gemm1(const float* __restrict__ x,
                                               const unsigned short* __restrict__ w1t,
                                               unsigned short* __restrict__ h1) {
  __shared__ char smem[49152];
  unsigned short* As = (unsigned short*)smem;
  unsigned short* Bs = (unsigned short*)(smem + 16384);
  const int tid = threadIdx.x;
  const int lane = tid & 63;
  const int wid = tid >> 6;
  const int wm = wid >> 2;
  const int wn = wid & 3;
  const long bm = blockIdx.x;

  const int ar0 = tid >> 3, as7 = tid & 7;
  const int ar1 = (tid + 512) >> 3;
  long arow0 = bm * 128 + ar0; if (arow0 > NN - 1) arow0 = NN - 1;
  long arow1 = bm * 128 + ar1; if (arow1 > NN - 1) arow1 = NN - 1;
  const float* gA0 = x + arow0 * INC + as7 * 8;
  const float* gA1 = x + arow1 * INC + as7 * 8;
  const int aoff0 = (ar0 << 7) | ((as7 ^ (ar0 & 7)) << 4);
  const int aoff1 = (ar1 << 7) | ((as7 ^ (ar1 & 7)) << 4);

  f32x4 acc[4][4];
#pragma unroll
  for (int m = 0; m < 4; m++)
#pragma unroll
    for (int n = 0; n < 4; n++) acc[m][n] = (f32x4){0.f, 0.f, 0.f, 0.f};

  float4 fa00, fa01, fa10, fa11;
  uint4 rb0, rb1, rb2, rb3;

#define LOAD_AB(KT)                                                        \
  do {                                                                     \
    fa00 = *(const float4*)(gA0 + (KT));                                   \
    fa01 = *(const float4*)(gA0 + (KT) + 4);                               \
    fa10 = *(const float4*)(gA1 + (KT));                                   \
    fa11 = *(const float4*)(gA1 + (KT) + 4);                               \
    rb0 = *(const uint4*)(w1t + (long)(tid >> 3) * INC + (KT) + (tid & 7) * 8);            \
    rb1 = *(const uint4*)(w1t + (long)((tid + 512) >> 3) * INC + (KT) + (tid & 7) * 8);    \
    rb2 = *(const uint4*)(w1t + (long)((tid + 1024) >> 3) * INC + (KT) + (tid & 7) * 8);   \
    rb3 = *(const uint4*)(w1t + (long)((tid + 1536) >> 3) * INC + (KT) + (tid & 7) * 8);   \
  } while (0)

  LOAD_AB(0);

  for (int kt = 0; kt < INC; kt += 64) {
    {
      union { unsigned short us[8]; uint4 v; } u;
      u.us[0] = f2bf(fa00.x); u.us[1] = f2bf(fa00.y); u.us[2] = f2bf(fa00.z); u.us[3] = f2bf(fa00.w);
      u.us[4] = f2bf(fa01.x); u.us[5] = f2bf(fa01.y); u.us[6] = f2bf(fa01.z); u.us[7] = f2bf(fa01.w);
      *(uint4*)((char*)As + aoff0) = u.v;
      u.us[0] = f2bf(fa10.x); u.us[1] = f2bf(fa10.y); u.us[2] = f2bf(fa10.z); u.us[3] = f2bf(fa10.w);
      u.us[4] = f2bf(fa11.x); u.us[5] = f2bf(fa11.y); u.us[6] = f2bf(fa11.z); u.us[7] = f2bf(fa11.w);
      *(uint4*)((char*)As + aoff1) = u.v;
    }
    {
      int r0 = tid >> 3, s7 = tid & 7;
      *(uint4*)((char*)Bs + ((r0 << 7) | ((s7 ^ (r0 & 7)) << 4))) = rb0;
      int r1 = (tid + 512) >> 3;
      *(uint4*)((char*)Bs + ((r1 << 7) | ((s7 ^ (r1 & 7)) << 4))) = rb1;
      int r2 = (tid + 1024) >> 3;
      *(uint4*)((char*)Bs + ((r2 << 7) | ((s7 ^ (r2 & 7)) << 4))) = rb2;
      int r3 = (tid + 1536) >> 3;
      *(uint4*)((char*)Bs + ((r3 << 7) | ((s7 ^ (r3 & 7)) << 4))) = rb3;
    }
    __syncthreads();
    if (kt + 64 < INC) LOAD_AB(kt + 64);
#pragma unroll
    for (int half = 0; half < 2; half++) {
      bf16x8 af[4], bff[4];
      int j = (half << 2) + (lane >> 4);
#pragma unroll
      for (int m = 0; m < 4; m++) {
        int row = wm * 64 + m * 16 + (lane & 15);
        int off = (row << 7) | ((j ^ (row & 7)) << 4);
        af[m] = *(const bf16x8*)((const char*)As + off);
      }
#pragma unroll
      for (int n = 0; n < 4; n++) {
        int row = wn * 64 + n * 16 + (lane & 15);
        int off = (row << 7) | ((j ^ (row & 7)) << 4);
        bff[n] = *(const bf16x8*)((const char*)Bs + off);
      }
#pragma unroll
      for (int m = 0; m < 4; m++)
#pragma unroll
        for (int n = 0; n < 4; n++)
          acc[m][n] = __builtin_amdgcn_mfma_f32_16x16x32_bf16(af[m], bff[n], acc[m][n], 0, 0, 0);
    }
    __syncthreads();
  }
#undef LOAD_AB

  unsigned short* Os = (unsigned short*)smem;  // [64][264]
#pragma unroll
  for (int chunk = 0; chunk < 2; chunk++) {
    if (wm == chunk) {
#pragma unroll
      for (int m = 0; m < 4; m++)
#pragma unroll
        for (int n = 0; n < 4; n++) {
          int lrow = m * 16 + ((lane >> 4) << 2);
          int lcol = wn * 64 + n * 16 + (lane & 15);
#pragma unroll
          for (int r = 0; r < 4; r++)
            Os[(lrow + r) * 264 + lcol] = f2bf(acc[m][n][r]);
        }
    }
    __syncthreads();
    {
      int r = tid >> 3, s = tid & 7;
      long grow = bm * 128 + chunk * 64 + r;
      if (grow < NN) {
        unsigned short* dst = h1 + grow * HID;
#pragma unroll
        for (int i = 0; i < 4; i++) {
          int seg = s + i * 8;
          *(uint4*)(dst + seg * 8) = *(const uint4*)((const char*)Os + (long)r * 528 + seg * 16);
        }
      }
    }
    __syncthreads();
  }
}

// ---------- agg1 fused with relu+b1+W2: wave/node, ushort4 gather, unroll x8 ----------
__global__ __launch_bounds__(256) void k_agg1(const unsigned short* __restrict__ h1,
                                              const float* __restrict__ dinv,
                                              const int* __restrict__ rowptr,
                                              const int2* __restrict__ epk,
                                              const float* __restrict__ b1,
                                              const float* __restrict__ W2,
                                              float* __restrict__ h2) {
  int w = (int)((blockIdx.x * 256 + threadIdx.x) >> 6);
  int lane = threadIdx.x & 63;
  if (w >= NN) return;
  float di = dinv[w];
  int c4 = lane << 2;
  const unsigned short* hb = h1 + c4;
  ushort4 hv = *(const ushort4*)(hb + (long)w * HID);
  float self = di * di;
  float a0 = self * bf2f(hv.x), a1 = self * bf2f(hv.y);
  float a2 = self * bf2f(hv.z), a3 = self * bf2f(hv.w);
  int e = rowptr[w], e1 = rowptr[w + 1];
  // parity peel so uint4 epk loads are 16B-aligned
  if ((e & 1) && e < e1) {
    int2 q = epk[e];
    float ws = __int_as_float(q.y);
    ushort4 g = *(const ushort4*)(hb + (long)q.x * HID);
    a0 += ws * bf2f(g.x); a1 += ws * bf2f(g.y);
    a2 += ws * bf2f(g.z); a3 += ws * bf2f(g.w);
    e++;
  }
  for (; e + 8 <= e1; e += 8) {
    uint4 p0 = *(const uint4*)(epk + e);
    uint4 p1 = *(const uint4*)(epk + e + 2);
    uint4 p2 = *(const uint4*)(epk + e + 4);
    uint4 p3 = *(const uint4*)(epk + e + 6);
    ushort4 g0 = *(const ushort4*)(hb + (long)(int)p0.x * HID);
    ushort4 g1 = *(const ushort4*)(hb + (long)(int)p0.z * HID);
    ushort4 g2 = *(const ushort4*)(hb + (long)(int)p1.x * HID);
    ushort4 g3 = *(const ushort4*)(hb + (long)(int)p1.z * HID);
    ushort4 g4 = *(const ushort4*)(hb + (long)(int)p2.x * HID);
    ushort4 g5 = *(const ushort4*)(hb + (long)(int)p2.z * HID);
    ushort4 g6 = *(const ushort4*)(hb + (long)(int)p3.x * HID);
    ushort4 g7 = *(const ushort4*)(hb + (long)(int)p3.z * HID);
    float w0 = __uint_as_float(p0.y), w1 = __uint_as_float(p0.w);
    float w2 = __uint_as_float(p1.y), w3 = __uint_as_float(p1.w);
    float w4 = __uint_as_float(p2.y), w5 = __uint_as_float(p2.w);
    float w6 = __uint_as_float(p3.y), w7 = __uint_as_float(p3.w);
    a0 += w0 * bf2f(g0.x) + w1 * bf2f(g1.x) + w2 * bf2f(g2.x) + w3 * bf2f(g3.x) +
          w4 * bf2f(g4.x) + w5 * bf2f(g5.x) + w6 * bf2f(g6.x) + w7 * bf2f(g7.x);
    a1 += w0 * bf2f(g0.y) + w1 * bf2f(g1.y) + w2 * bf2f(g2.y) + w3 * bf2f(g3.y) +
          w4 * bf2f(g4.y) + w5 * bf2f(g5.y) + w6 * bf2f(g6.y) + w7 * bf2f(g7.y);
    a2 += w0 * bf2f(g0.z) + w1 * bf2f(g1.z) + w2 * bf2f(g2.z) + w3 * bf2f(g3.z) +
          w4 * bf2f(g4.z) + w5 * bf2f(g5.z) + w6 * bf2f(g6.z) + w7 * bf2f(g7.z);
    a3 += w0 * bf2f(g0.w) + w1 * bf2f(g1.w) + w2 * bf2f(g2.w) + w3 * bf2f(g3.w) +
          w4 * bf2f(g4.w) + w5 * bf2f(g5.w) + w6 * bf2f(g6.w) + w7 * bf2f(g7.w);
  }
  for (; e + 2 <= e1; e += 2) {
    uint4 p = *(const uint4*)(epk + e);
    ushort4 g0 = *(const ushort4*)(hb + (long)(int)p.x * HID);
    ushort4 g1 = *(const ushort4*)(hb + (long)(int)p.z * HID);
    float w0 = __uint_as_float(p.y), w1 = __uint_as_float(p.w);
    a0 += w0 * bf2f(g0.x) + w1 * bf2f(g1.x);
    a1 += w0 * bf2f(g0.y) + w1 * bf2f(g1.y);
    a2 += w0 * bf2f(g0.z) + w1 * bf2f(g1.z);
    a3 += w0 * bf2f(g0.w) + w1 * bf2f(g1.w);
  }
  if (e < e1) {
    int2 q = epk[e];
    float ws = __int_as_float(q.y);
    ushort4 g = *(const ushort4*)(hb + (long)q.x * HID);
    a0 += ws * bf2f(g.x); a1 += ws * bf2f(g.y);
    a2 += ws * bf2f(g.z); a3 += ws * bf2f(g.w);
  }
  // relu(a + b1), then 4ch x 8cls partials
  float4 bv = *(const float4*)(b1 + c4);
  float v0 = a0 + bv.x; v0 = v0 > 0.f ? v0 : 0.f;
  float v1 = a1 + bv.y; v1 = v1 > 0.f ? v1 : 0.f;
  float v2 = a2 + bv.z; v2 = v2 > 0.f ? v2 : 0.f;
  float v3 = a3 + bv.w; v3 = v3 > 0.f ? v3 : 0.f;
  const float4* wp = (const float4*)(W2 + ((long)c4 << 3));
  float4 r0a = wp[0], r0b = wp[1], r1a = wp[2], r1b = wp[3];
  float4 r2a = wp[4], r2b = wp[5], r3a = wp[6], r3b = wp[7];
  float p[8];
  p[0] = v0 * r0a.x + v1 * r1a.x + v2 * r2a.x + v3 * r3a.x;
  p[1] = v0 * r0a.y + v1 * r1a.y + v2 * r2a.y + v3 * r3a.y;
  p[2] = v0 * r0a.z + v1 * r1a.z + v2 * r2a.z + v3 * r3a.z;
  p[3] = v0 * r0a.w + v1 * r1a.w + v2 * r2a.w + v3 * r3a.w;
  p[4] = v0 * r0b.x + v1 * r1b.x + v2 * r2b.x + v3 * r3b.x;
  p[5] = v0 * r0b.y + v1 * r1b.y + v2 * r2b.y + v3 * r3b.y;
  p[6] = v0 * r0b.z + v1 * r1b.z + v2 * r2b.z + v3 * r3b.z;
  p[7] = v0 * r0b.w + v1 * r1b.w + v2 * r2b.w + v3 * r3b.w;
#pragma unroll
  for (int c = 0; c < 8; c++)
#pragma unroll
    for (int off = 1; off < 64; off <<= 1) p[c] += __shfl_xor(p[c], off, 64);
  if (lane < 8) {
    float o = p[0];
    o = (lane == 1) ? p[1] : o;
    o = (lane == 2) ? p[2] : o;
    o = (lane == 3) ? p[3] : o;
    o = (lane == 4) ? p[4] : o;
    o = (lane == 5) ? p[5] : o;
    o = (lane == 6) ? p[6] : o;
    o = (lane == 7) ? p[7] : o;
    h2[(long)w * NCLS + lane] = o;
  }
}

// ---------- agg2 + bias -> out (unroll x8) ----------
__global__ __launch_bounds__(256) void k_agg2(const float* __restrict__ h2,
                                              const float* __restrict__ dinv,
                                              const int* __restrict__ rowptr,
                                              const int2* __restrict__ epk,
                                              const float* __restrict__ b2,
                                              float* __restrict__ out) {
  long t = (long)blockIdx.x * 256 + threadIdx.x;
  long i = t >> 3;
  int c = (int)(t & 7);
  if (i >= NN) return;
  float di = dinv[i];
  float s = di * di * h2[i * NCLS + c];
  int e = rowptr[i], e1 = rowptr[i + 1];
  for (; e + 8 <= e1; e += 8) {
    int2 q0 = epk[e],     q1 = epk[e + 1], q2 = epk[e + 2], q3 = epk[e + 3];
    int2 q4 = epk[e + 4], q5 = epk[e + 5], q6 = epk[e + 6], q7 = epk[e + 7];
    float g0 = h2[(long)q0.x * NCLS + c], g1 = h2[(long)q1.x * NCLS + c];
    float g2 = h2[(long)q2.x * NCLS + c], g3 = h2[(long)q3.x * NCLS + c];
    float g4 = h2[(long)q4.x * NCLS + c], g5 = h2[(long)q5.x * NCLS + c];
    float g6 = h2[(long)q6.x * NCLS + c], g7 = h2[(long)q7.x * NCLS + c];
    s += __int_as_float(q0.y) * g0 + __int_as_float(q1.y) * g1 +
         __int_as_float(q2.y) * g2 + __int_as_float(q3.y) * g3 +
         __int_as_float(q4.y) * g4 + __int_as_float(q5.y) * g5 +
         __int_as_float(q6.y) * g6 + __int_as_float(q7.y) * g7;
  }
  for (; e < e1; e++) {
    int2 q = epk[e];
    s += __int_as_float(q.y) * h2[(long)q.x * NCLS + c];
  }
  out[i * NCLS + c] = s + b2[c];
}

extern "C" void kernel_launch(void* const* d_in, const int* in_sizes, int n_in,
                              void* d_out, int out_size, void* d_ws, size_t ws_size,
                              hipStream_t stream) {
  (void)in_sizes; (void)n_in; (void)out_size; (void)ws_size;
  const float* x  = (const float*)d_in[0];
  const int*   ei = (const int*)d_in[1];
  const float* W1 = (const float*)d_in[2];
  const float* b1 = (const float*)d_in[3];
  const float* W2 = (const float*)d_in[4];
  const float* b2 = (const float*)d_in[5];
  float* out = (float*)d_out;
  char* ws = (char*)d_ws;

  unsigned short* h1   = (unsigned short*)(ws + 0L);          // 51,200,000
  float* h2            = (float*)(ws + 51200000L);            // 3,200,000
  float* dinv          = (float*)(ws + 54400000L);            // 400,000
  int*   cnt           = (int*)(ws + 54800000L);              // 400,000
  int*   rowptr        = (int*)(ws + 55200000L);              // 400,004 (+pad)
  int*   cursor        = (int*)(ws + 55600128L);              // 400,000
  int2*  epk           = (int2*)(ws + 56000128L);             // 12,800,000
  unsigned short* w1t  = (unsigned short*)(ws + 68800128L);   // 393,216
  int*   bsum          = (int*)(ws + 69195008L);              // 1,564
  int*   boff          = (int*)(ws + 69196608L);              // 1,564

  hipMemsetAsync(cnt, 0, NN * sizeof(int), stream);
  k_count<<<(NE + 255) / 256, 256, 0, stream>>>(ei, cnt);
  k_scan1<<<NBLK, 256, 0, stream>>>(cnt, bsum, dinv);
  k_scan2<<<1, 512, 0, stream>>>(bsum, boff, rowptr);
  k_scan3<<<NBLK, 256, 0, stream>>>(cnt, boff, rowptr, cursor);
  k_fill<<<(NE + 255) / 256, 256, 0, stream>>>(ei, dinv, cursor, epk);
  k_w1t<<<(INC * HID + 255) / 256, 256, 0, stream>>>(W1, w1t);
  k_gemm1<<<782, 512, 0, stream>>>(x, w1t, h1);
  k_agg1<<<(NN * 64 + 255) / 256, 256, 0, stream>>>(h1, dinv, rowptr, epk, b1, W2, h2);
  k_agg2<<<(NN * NCLS + 255) / 256, 256, 0, stream>>>(h2, dinv, rowptr, epk, b2, out);
}